// Round 1
// baseline (1021.339 us; speedup 1.0000x reference)
//
#include <hip/hip_runtime.h>
#include <hip/hip_bf16.h>

#define NN 100000
#define EE 640000

typedef short bf16x8 __attribute__((ext_vector_type(8)));
typedef float f32x4 __attribute__((ext_vector_type(4)));

__device__ __forceinline__ ushort f2bf(float f){
  uint u = __float_as_uint(f);
  u += 0x7fffu + ((u >> 16) & 1u);   // round-to-nearest-even
  return (ushort)(u >> 16);
}
__device__ __forceinline__ float bf2f(ushort s){ return __uint_as_float(((uint)s) << 16); }
__device__ __forceinline__ uint pack2(float a, float b){ return ((uint)f2bf(b) << 16) | (uint)f2bf(a); }
// XOR swizzle: spreads stride-256B/512B row-major rows across LDS bank groups (G4)
__device__ __forceinline__ uint swz(uint row, uint colB, uint strideB){
  return row * strideB + (colB ^ ((row & 7u) << 4));
}

// ---------------- K0: weight prep (fp32 -> bf16, transposed [col][k]) + zero a_sum ----
__global__ void k_prep(const float* __restrict__ Wq, const float* __restrict__ Wk,
                       const float* __restrict__ Wv, const float* __restrict__ Wsk,
                       const float* __restrict__ We,
                       ushort* __restrict__ W4t, ushort* __restrict__ Wet,
                       float* __restrict__ a_sum){
  int tid = blockIdx.x * 256 + threadIdx.x;
  if (tid < 512 * 128){              // W4t[col 0..511][k 0..127], cols: q|k|v|skip
    int col = tid >> 7, k = tid & 127;
    const float* W = (col < 128) ? Wq : ((col < 256) ? Wk : ((col < 384) ? Wv : Wsk));
    W4t[tid] = f2bf(W[k * 128 + (col & 127)]);
  }
  if (tid < 128 * 256){              // Wet[col 0..127][k 0..255]
    int col = tid >> 8, k = tid & 255;
    Wet[tid] = f2bf(We[k * 128 + col]);
  }
  if (tid < NN * 2) a_sum[tid] = 0.f;
}

// ---------------- K1: node GEMM x@[Wq|Wk|Wv|Wskip], 64-row tiles, bf16 MFMA ----------
__global__ __launch_bounds__(256) void k_node(
    const float* __restrict__ x, const ushort* __restrict__ W4t,
    const float* __restrict__ bq, const float* __restrict__ bk,
    const float* __restrict__ bv, const float* __restrict__ bsk,
    ushort* __restrict__ q_n, ushort* __restrict__ k_n, ushort* __restrict__ v_n,
    float* __restrict__ out){
  __shared__ ushort As[64 * 128];    // [row][k], 256B rows, swizzled
  __shared__ ushort Bs[128 * 128];   // [col][k], 256B rows, swizzled
  char* Ab = (char*)As; char* Bb = (char*)Bs;
  int tid = threadIdx.x;
  int n0 = blockIdx.x * 64;
  { // stage A: x rows -> bf16 LDS
    int row = tid >> 2, part = tid & 3;
    int gr = n0 + row;
    for (int j = 0; j < 4; j++){
      float4 a = make_float4(0.f,0.f,0.f,0.f), b = a;
      if (gr < NN){
        const float4* p = (const float4*)(x + (size_t)gr * 128 + part * 32 + j * 8);
        a = p[0]; b = p[1];
      }
      uint4 w; w.x = pack2(a.x,a.y); w.y = pack2(a.z,a.w); w.z = pack2(b.x,b.y); w.w = pack2(b.z,b.w);
      *(uint4*)(Ab + swz(row, (uint)(part * 64 + j * 16), 256)) = w;
    }
  }
  int wid = tid >> 6, l = tid & 63, lr = l & 15, lg = l >> 4;
  for (int chunk = 0; chunk < 4; ++chunk){
    if (chunk) __syncthreads();      // readers of previous Bs done
    { // stage B chunk: W4t[chunk*128 .. +128][0..128]
      int row = tid >> 1, half = tid & 1;
      const ushort* src = W4t + (size_t)(chunk * 128 + row) * 128 + half * 64;
      for (int j = 0; j < 8; j++){
        uint4 w = *(const uint4*)(src + j * 8);
        *(uint4*)(Bb + swz(row, (uint)(half * 128 + j * 16), 256)) = w;
      }
    }
    __syncthreads();
    f32x4 acc[8];
    for (int i = 0; i < 8; i++) acc[i] = (f32x4){0.f,0.f,0.f,0.f};
    for (int ks = 0; ks < 4; ++ks){
      bf16x8 a = *(bf16x8*)(Ab + swz(wid * 16 + lr, (uint)(ks * 64 + lg * 16), 256));
      for (int cf = 0; cf < 8; ++cf){
        bf16x8 b = *(bf16x8*)(Bb + swz(cf * 16 + lr, (uint)(ks * 64 + lg * 16), 256));
        acc[cf] = __builtin_amdgcn_mfma_f32_16x16x32_bf16(a, b, acc[cf], 0, 0, 0);
      }
    }
    for (int cf = 0; cf < 8; ++cf){
      for (int i = 0; i < 4; i++){
        int row = wid * 16 + lg * 4 + i;
        int gr = n0 + row;
        if (gr >= NN) continue;
        int col = cf * 16 + lr;
        float v = acc[cf][i];
        if (chunk == 0)      q_n[(size_t)gr * 128 + col] = f2bf(v + bq[col]);
        else if (chunk == 1) k_n[(size_t)gr * 128 + col] = f2bf(v + bk[col]);
        else if (chunk == 2) v_n[(size_t)gr * 128 + col] = f2bf(v + bv[col]);
        else                 out[(size_t)gr * 128 + col] = v + bsk[col];  // skip init
      }
    }
  }
}

// ---------------- K2: edge GEMM edge_attr@We -> e_proj (bf16), 64-edge tiles ---------
__global__ __launch_bounds__(256) void k_edge(
    const float* __restrict__ t, const float* __restrict__ lu,
    const float* __restrict__ msg, const float* __restrict__ tw,
    const float* __restrict__ tb, const int* __restrict__ ei,
    const ushort* __restrict__ Wet, ushort* __restrict__ ep){
  __shared__ ushort As[64 * 256];    // [edge][k 0..255], 512B rows, swizzled
  __shared__ ushort Ws[128 * 128];   // [col][k-half], 256B rows, swizzled
  char* Ab = (char*)As; char* Wb = (char*)Ws;
  int tid = threadIdx.x;
  int e0 = blockIdx.x * 64;
  { // stage A: cols 0-127 = cos(rel_t*w+b), cols 128-255 = msg
    int er = tid >> 2, part = tid & 3;
    int e = e0 + er;
    int src = ei[e];
    float rel = t[e] - lu[src];
    if (part < 2){
      int cb = part * 64;
      for (int j = 0; j < 8; j++){
        const float4* wp = (const float4*)(tw + cb + j * 8);
        const float4* bp = (const float4*)(tb + cb + j * 8);
        float4 w0 = wp[0], w1 = wp[1], b0 = bp[0], b1 = bp[1];
        float c0 = __cosf(fmaf(rel, w0.x, b0.x));
        float c1 = __cosf(fmaf(rel, w0.y, b0.y));
        float c2 = __cosf(fmaf(rel, w0.z, b0.z));
        float c3 = __cosf(fmaf(rel, w0.w, b0.w));
        float c4 = __cosf(fmaf(rel, w1.x, b1.x));
        float c5 = __cosf(fmaf(rel, w1.y, b1.y));
        float c6 = __cosf(fmaf(rel, w1.z, b1.z));
        float c7 = __cosf(fmaf(rel, w1.w, b1.w));
        uint4 w; w.x = pack2(c0,c1); w.y = pack2(c2,c3); w.z = pack2(c4,c5); w.w = pack2(c6,c7);
        *(uint4*)(Ab + swz(er, (uint)((cb + j * 8) * 2), 512)) = w;
      }
    } else {
      int cb = (part - 2) * 64;
      for (int j = 0; j < 8; j++){
        const float4* p = (const float4*)(msg + (size_t)e * 128 + cb + j * 8);
        float4 a = p[0], b = p[1];
        uint4 w; w.x = pack2(a.x,a.y); w.y = pack2(a.z,a.w); w.z = pack2(b.x,b.y); w.w = pack2(b.z,b.w);
        *(uint4*)(Ab + swz(er, (uint)((128 + cb + j * 8) * 2), 512)) = w;
      }
    }
  }
  int wid = tid >> 6, l = tid & 63, lr = l & 15, lg = l >> 4;
  f32x4 acc[8];
  for (int i = 0; i < 8; i++) acc[i] = (f32x4){0.f,0.f,0.f,0.f};
  for (int kh = 0; kh < 2; ++kh){
    if (kh) __syncthreads();         // readers of previous Ws done
    { // stage We half: Wet[col][kh*128 .. +128]
      int row = tid >> 1, half = tid & 1;
      const ushort* src = Wet + (size_t)row * 256 + kh * 128 + half * 64;
      for (int j = 0; j < 8; j++){
        uint4 w = *(const uint4*)(src + j * 8);
        *(uint4*)(Wb + swz(row, (uint)(half * 128 + j * 16), 256)) = w;
      }
    }
    __syncthreads();                 // A (first iter) + Ws staged
    for (int ks = 0; ks < 4; ++ks){
      bf16x8 a = *(bf16x8*)(Ab + swz(wid * 16 + lr, (uint)(kh * 256 + ks * 64 + lg * 16), 512));
      for (int cf = 0; cf < 8; ++cf){
        bf16x8 b = *(bf16x8*)(Wb + swz(cf * 16 + lr, (uint)(ks * 64 + lg * 16), 256));
        acc[cf] = __builtin_amdgcn_mfma_f32_16x16x32_bf16(a, b, acc[cf], 0, 0, 0);
      }
    }
  }
  for (int cf = 0; cf < 8; ++cf)
    for (int i = 0; i < 4; i++){
      int row = wid * 16 + lg * 4 + i;
      int col = cf * 16 + lr;
      ep[(size_t)(e0 + row) * 128 + col] = f2bf(acc[cf][i]);
    }
}

// ---------------- K3: per-edge logits, exp, atomic denominator ------------------------
__global__ __launch_bounds__(256) void k_alpha(
    const ushort* __restrict__ q_n, const ushort* __restrict__ k_n,
    const ushort* __restrict__ ep, const int* __restrict__ ei,
    float* __restrict__ a_exp, float* __restrict__ a_sum){
  int gid = blockIdx.x * 256 + threadIdx.x;
  int e = gid >> 6;
  if (e >= EE) return;
  int l = gid & 63;                  // lane handles channels 2l, 2l+1; head = l>>5
  int src = ei[e], dst = ei[EE + e];
  int c = l * 2;
  uint qq = *(const uint*)(q_n + (size_t)dst * 128 + c);
  uint kk = *(const uint*)(k_n + (size_t)src * 128 + c);
  uint pp = *(const uint*)(ep  + (size_t)e   * 128 + c);
  float part = bf2f(qq & 0xffff) * (bf2f(kk & 0xffff) + bf2f(pp & 0xffff))
             + bf2f(qq >> 16)    * (bf2f(kk >> 16)    + bf2f(pp >> 16));
  for (int off = 16; off > 0; off >>= 1) part += __shfl_xor(part, off, 32);
  if ((l & 31) == 0){
    int h = l >> 5;
    float ae = expf(part * 0.125f);  // 1/sqrt(64); no max-subtraction needed (alpha ~ N(0,0.55^2))
    a_exp[(size_t)e * 2 + h] = ae;
    unsafeAtomicAdd(&a_sum[(size_t)dst * 2 + h], ae);
  }
}

// ---------------- K4: normalize + weighted scatter into out ---------------------------
__global__ __launch_bounds__(256) void k_out(
    const ushort* __restrict__ v_n, const ushort* __restrict__ ep,
    const int* __restrict__ ei, const float* __restrict__ a_exp,
    const float* __restrict__ a_sum, float* __restrict__ out){
  int gid = blockIdx.x * 256 + threadIdx.x;
  int e = gid >> 6;
  if (e >= EE) return;
  int l = gid & 63;
  int src = ei[e], dst = ei[EE + e];
  int h = l >> 5;
  float attn = a_exp[(size_t)e * 2 + h] / (a_sum[(size_t)dst * 2 + h] + 1e-16f);
  int c = l * 2;
  uint vv = *(const uint*)(v_n + (size_t)src * 128 + c);
  uint pp = *(const uint*)(ep  + (size_t)e   * 128 + c);
  float o0 = attn * (bf2f(vv & 0xffff) + bf2f(pp & 0xffff));
  float o1 = attn * (bf2f(vv >> 16)    + bf2f(pp >> 16));
  unsafeAtomicAdd(&out[(size_t)dst * 128 + c],     o0);
  unsafeAtomicAdd(&out[(size_t)dst * 128 + c + 1], o1);
}

extern "C" void kernel_launch(void* const* d_in, const int* in_sizes, int n_in,
                              void* d_out, int out_size, void* d_ws, size_t ws_size,
                              hipStream_t stream) {
  const float* x   = (const float*)d_in[0];
  const float* lu  = (const float*)d_in[1];
  const float* t   = (const float*)d_in[2];
  const float* msg = (const float*)d_in[3];
  const float* tw  = (const float*)d_in[4];
  const float* tb  = (const float*)d_in[5];
  const float* Wq  = (const float*)d_in[6];
  const float* bq  = (const float*)d_in[7];
  const float* Wk  = (const float*)d_in[8];
  const float* bk  = (const float*)d_in[9];
  const float* Wv  = (const float*)d_in[10];
  const float* bv  = (const float*)d_in[11];
  const float* We  = (const float*)d_in[12];
  const float* Wsk = (const float*)d_in[13];
  const float* bsk = (const float*)d_in[14];
  const int*   ei  = (const int*)d_in[15];
  float* out = (float*)d_out;

  char* w = (char*)d_ws;
  size_t off = 0;
  auto nxt = [&](size_t b){ size_t r = off; off += (b + 255) & ~(size_t)255; return r; };
  ushort* q_n  = (ushort*)(w + nxt((size_t)NN * 128 * 2));
  ushort* k_n  = (ushort*)(w + nxt((size_t)NN * 128 * 2));
  ushort* v_n  = (ushort*)(w + nxt((size_t)NN * 128 * 2));
  ushort* epj  = (ushort*)(w + nxt((size_t)EE * 128 * 2));
  float*  aex  = (float*) (w + nxt((size_t)EE * 2 * 4));
  float*  asum = (float*) (w + nxt((size_t)NN * 2 * 4));
  ushort* W4t  = (ushort*)(w + nxt((size_t)512 * 128 * 2));
  ushort* Wet  = (ushort*)(w + nxt((size_t)128 * 256 * 2));

  k_prep<<<(NN * 2 + 255) / 256, 256, 0, stream>>>(Wq, Wk, Wv, Wsk, We, W4t, Wet, asum);
  k_node<<<(NN + 63) / 64, 256, 0, stream>>>(x, W4t, bq, bk, bv, bsk, q_n, k_n, v_n, out);
  k_edge<<<EE / 64, 256, 0, stream>>>(t, lu, msg, tw, tb, ei, Wet, epj);
  k_alpha<<<EE / 4, 256, 0, stream>>>(q_n, k_n, epj, ei, aex, asum);
  k_out<<<EE / 4, 256, 0, stream>>>(v_n, epj, ei, aex, asum, out);
}

// Round 2
// 603.021 us; speedup vs baseline: 1.6937x; 1.6937x over previous
//
#include <hip/hip_runtime.h>
#include <hip/hip_bf16.h>

#define NN 100000
#define EE 640000
#define NB_SCAN 98   // ceil(NN/1024)

typedef short bf16x8 __attribute__((ext_vector_type(8)));
typedef float f32x4 __attribute__((ext_vector_type(4)));

__device__ __forceinline__ ushort f2bf(float f){
  uint u = __float_as_uint(f);
  u += 0x7fffu + ((u >> 16) & 1u);   // round-to-nearest-even
  return (ushort)(u >> 16);
}
__device__ __forceinline__ float bf2f(ushort s){ return __uint_as_float(((uint)s) << 16); }
__device__ __forceinline__ uint pack2(float a, float b){ return ((uint)f2bf(b) << 16) | (uint)f2bf(a); }
// XOR swizzle: spreads stride-256B/512B row-major rows across LDS bank groups (G4)
__device__ __forceinline__ uint swz(uint row, uint colB, uint strideB){
  return row * strideB + (colB ^ ((row & 7u) << 4));
}

// ---------------- K0: weight prep (fp32 -> bf16, transposed [col][k]) + zero deg -----
__global__ void k_prep(const float* __restrict__ Wq, const float* __restrict__ Wk,
                       const float* __restrict__ Wv, const float* __restrict__ Wsk,
                       const float* __restrict__ We,
                       ushort* __restrict__ W4t, ushort* __restrict__ Wet,
                       int* __restrict__ deg){
  int tid = blockIdx.x * 256 + threadIdx.x;
  if (tid < 512 * 128){              // W4t[col 0..511][k 0..127], cols: q|k|v|skip
    int col = tid >> 7, k = tid & 127;
    const float* W = (col < 128) ? Wq : ((col < 256) ? Wk : ((col < 384) ? Wv : Wsk));
    W4t[tid] = f2bf(W[k * 128 + (col & 127)]);
  }
  if (tid < 128 * 256){              // Wet[col 0..127][k 0..255]
    int col = tid >> 8, k = tid & 255;
    Wet[tid] = f2bf(We[k * 128 + col]);
  }
  if (tid < NN) deg[tid] = 0;
}

// ---------------- K1: node GEMM x@[Wq|Wk|Wv|Wskip], 64-row tiles, bf16 MFMA ----------
// q -> q_n[node][128]; k,v interleaved -> kv[node][64 pairs][k0,k1,v0,v1]; skip -> out
__global__ __launch_bounds__(256) void k_node(
    const float* __restrict__ x, const ushort* __restrict__ W4t,
    const float* __restrict__ bq, const float* __restrict__ bk,
    const float* __restrict__ bv, const float* __restrict__ bsk,
    ushort* __restrict__ q_n, ushort* __restrict__ kv,
    float* __restrict__ out){
  __shared__ ushort As[64 * 128];    // [row][k], 256B rows, swizzled
  __shared__ ushort Bs[128 * 128];   // [col][k], 256B rows, swizzled
  char* Ab = (char*)As; char* Bb = (char*)Bs;
  int tid = threadIdx.x;
  int n0 = blockIdx.x * 64;
  { // stage A: x rows -> bf16 LDS
    int row = tid >> 2, part = tid & 3;
    int gr = n0 + row;
    for (int j = 0; j < 4; j++){
      float4 a = make_float4(0.f,0.f,0.f,0.f), b = a;
      if (gr < NN){
        const float4* p = (const float4*)(x + (size_t)gr * 128 + part * 32 + j * 8);
        a = p[0]; b = p[1];
      }
      uint4 w; w.x = pack2(a.x,a.y); w.y = pack2(a.z,a.w); w.z = pack2(b.x,b.y); w.w = pack2(b.z,b.w);
      *(uint4*)(Ab + swz(row, (uint)(part * 64 + j * 16), 256)) = w;
    }
  }
  int wid = tid >> 6, l = tid & 63, lr = l & 15, lg = l >> 4;
  for (int chunk = 0; chunk < 4; ++chunk){
    if (chunk) __syncthreads();      // readers of previous Bs done
    { // stage B chunk: W4t[chunk*128 .. +128][0..128]
      int row = tid >> 1, half = tid & 1;
      const ushort* src = W4t + (size_t)(chunk * 128 + row) * 128 + half * 64;
      for (int j = 0; j < 8; j++){
        uint4 w = *(const uint4*)(src + j * 8);
        *(uint4*)(Bb + swz(row, (uint)(half * 128 + j * 16), 256)) = w;
      }
    }
    __syncthreads();
    f32x4 acc[8];
    for (int i = 0; i < 8; i++) acc[i] = (f32x4){0.f,0.f,0.f,0.f};
    for (int ks = 0; ks < 4; ++ks){
      bf16x8 a = *(bf16x8*)(Ab + swz(wid * 16 + lr, (uint)(ks * 64 + lg * 16), 256));
      for (int cf = 0; cf < 8; ++cf){
        bf16x8 b = *(bf16x8*)(Bb + swz(cf * 16 + lr, (uint)(ks * 64 + lg * 16), 256));
        acc[cf] = __builtin_amdgcn_mfma_f32_16x16x32_bf16(a, b, acc[cf], 0, 0, 0);
      }
    }
    for (int cf = 0; cf < 8; ++cf){
      for (int i = 0; i < 4; i++){
        int row = wid * 16 + lg * 4 + i;
        int gr = n0 + row;
        if (gr >= NN) continue;
        int col = cf * 16 + lr;
        float v = acc[cf][i];
        if (chunk == 0)      q_n[(size_t)gr * 128 + col] = f2bf(v + bq[col]);
        else if (chunk == 1) kv[(size_t)gr * 256 + ((col >> 1) << 2) + (col & 1)]     = f2bf(v + bk[col]);
        else if (chunk == 2) kv[(size_t)gr * 256 + ((col >> 1) << 2) + 2 + (col & 1)] = f2bf(v + bv[col]);
        else                 out[(size_t)gr * 128 + col] = v + bsk[col];  // skip init
      }
    }
  }
}

// ---------------- K2: edge GEMM edge_attr@We -> e_proj (bf16), 64-edge tiles ---------
__global__ __launch_bounds__(256) void k_edge(
    const float* __restrict__ t, const float* __restrict__ lu,
    const float* __restrict__ msg, const float* __restrict__ tw,
    const float* __restrict__ tb, const int* __restrict__ ei,
    const ushort* __restrict__ Wet, ushort* __restrict__ ep){
  __shared__ ushort As[64 * 256];    // [edge][k 0..255], 512B rows, swizzled
  __shared__ ushort Ws[128 * 128];   // [col][k-half], 256B rows, swizzled
  char* Ab = (char*)As; char* Wb = (char*)Ws;
  int tid = threadIdx.x;
  int e0 = blockIdx.x * 64;
  { // stage A: cols 0-127 = cos(rel_t*w+b), cols 128-255 = msg
    int er = tid >> 2, part = tid & 3;
    int e = e0 + er;
    int src = ei[e];
    float rel = t[e] - lu[src];
    if (part < 2){
      int cb = part * 64;
      for (int j = 0; j < 8; j++){
        const float4* wp = (const float4*)(tw + cb + j * 8);
        const float4* bp = (const float4*)(tb + cb + j * 8);
        float4 w0 = wp[0], w1 = wp[1], b0 = bp[0], b1 = bp[1];
        float c0 = __cosf(fmaf(rel, w0.x, b0.x));
        float c1 = __cosf(fmaf(rel, w0.y, b0.y));
        float c2 = __cosf(fmaf(rel, w0.z, b0.z));
        float c3 = __cosf(fmaf(rel, w0.w, b0.w));
        float c4 = __cosf(fmaf(rel, w1.x, b1.x));
        float c5 = __cosf(fmaf(rel, w1.y, b1.y));
        float c6 = __cosf(fmaf(rel, w1.z, b1.z));
        float c7 = __cosf(fmaf(rel, w1.w, b1.w));
        uint4 w; w.x = pack2(c0,c1); w.y = pack2(c2,c3); w.z = pack2(c4,c5); w.w = pack2(c6,c7);
        *(uint4*)(Ab + swz(er, (uint)((cb + j * 8) * 2), 512)) = w;
      }
    } else {
      int cb = (part - 2) * 64;
      for (int j = 0; j < 8; j++){
        const float4* p = (const float4*)(msg + (size_t)e * 128 + cb + j * 8);
        float4 a = p[0], b = p[1];
        uint4 w; w.x = pack2(a.x,a.y); w.y = pack2(a.z,a.w); w.z = pack2(b.x,b.y); w.w = pack2(b.z,b.w);
        *(uint4*)(Ab + swz(er, (uint)((128 + cb + j * 8) * 2), 512)) = w;
      }
    }
  }
  int wid = tid >> 6, l = tid & 63, lr = l & 15, lg = l >> 4;
  f32x4 acc[8];
  for (int i = 0; i < 8; i++) acc[i] = (f32x4){0.f,0.f,0.f,0.f};
  for (int kh = 0; kh < 2; ++kh){
    if (kh) __syncthreads();         // readers of previous Ws done
    { // stage We half: Wet[col][kh*128 .. +128]
      int row = tid >> 1, half = tid & 1;
      const ushort* src = Wet + (size_t)row * 256 + kh * 128 + half * 64;
      for (int j = 0; j < 8; j++){
        uint4 w = *(const uint4*)(src + j * 8);
        *(uint4*)(Wb + swz(row, (uint)(half * 128 + j * 16), 256)) = w;
      }
    }
    __syncthreads();                 // A (first iter) + Ws staged
    for (int ks = 0; ks < 4; ++ks){
      bf16x8 a = *(bf16x8*)(Ab + swz(wid * 16 + lr, (uint)(kh * 256 + ks * 64 + lg * 16), 512));
      for (int cf = 0; cf < 8; ++cf){
        bf16x8 b = *(bf16x8*)(Wb + swz(cf * 16 + lr, (uint)(ks * 64 + lg * 16), 256));
        acc[cf] = __builtin_amdgcn_mfma_f32_16x16x32_bf16(a, b, acc[cf], 0, 0, 0);
      }
    }
  }
  for (int cf = 0; cf < 8; ++cf)
    for (int i = 0; i < 4; i++){
      int row = wid * 16 + lg * 4 + i;
      int col = cf * 16 + lr;
      ep[(size_t)(e0 + row) * 128 + col] = f2bf(acc[cf][i]);
    }
}

// ---------------- Sort: histogram -> 2-level exclusive scan -> placement --------------
__global__ void k_hist(const int* __restrict__ ei, int* __restrict__ deg){
  int e = blockIdx.x * 256 + threadIdx.x;
  if (e < EE) atomicAdd(&deg[ei[EE + e]], 1);
}

__global__ __launch_bounds__(256) void k_scan1(const int* __restrict__ deg,
                                               int* __restrict__ start,
                                               int* __restrict__ partial){
  __shared__ int sums[256];
  int b = blockIdx.x, tid = threadIdx.x;
  int base = b * 1024 + tid * 4;
  int d0 = (base + 0 < NN) ? deg[base + 0] : 0;
  int d1 = (base + 1 < NN) ? deg[base + 1] : 0;
  int d2 = (base + 2 < NN) ? deg[base + 2] : 0;
  int d3 = (base + 3 < NN) ? deg[base + 3] : 0;
  int s = d0 + d1 + d2 + d3;
  sums[tid] = s;
  __syncthreads();
  for (int off = 1; off < 256; off <<= 1){
    int v = (tid >= off) ? sums[tid - off] : 0;
    __syncthreads();
    sums[tid] += v;
    __syncthreads();
  }
  int excl = sums[tid] - s;          // exclusive prefix within block
  if (base + 0 < NN) start[base + 0] = excl;
  if (base + 1 < NN) start[base + 1] = excl + d0;
  if (base + 2 < NN) start[base + 2] = excl + d0 + d1;
  if (base + 3 < NN) start[base + 3] = excl + d0 + d1 + d2;
  if (tid == 255) partial[b] = sums[255];
}

__global__ void k_scan2(int* __restrict__ partial){
  if (threadIdx.x == 0){
    int run = 0;
    for (int b = 0; b < NB_SCAN; b++){ int t = partial[b]; partial[b] = run; run += t; }
  }
}

__global__ void k_scan3(int* __restrict__ start, const int* __restrict__ partial,
                        int* __restrict__ cursor){
  int i = blockIdx.x * 256 + threadIdx.x;
  if (i < NN){
    int v = start[i] + partial[i >> 10];
    start[i] = v;
    cursor[i] = v;
  }
  if (i == 0) start[NN] = EE;
}

__global__ void k_place(const int* __restrict__ ei, int* __restrict__ cursor,
                        int* __restrict__ sorted){
  int e = blockIdx.x * 256 + threadIdx.x;
  if (e < EE){
    int dst = ei[EE + e];
    int pos = atomicAdd(&cursor[dst], 1);
    sorted[pos] = e;
  }
}

// ---------------- K3: per-node gather: logits, softmax, weighted sum ------------------
// one 64-lane wave per dst node; lane l owns channels 2l,2l+1 (head = l>>5)
__global__ __launch_bounds__(256) void k_gather(
    const ushort* __restrict__ q_n, const ushort* __restrict__ kv,
    const ushort* __restrict__ ep, const int* __restrict__ ei,
    const int* __restrict__ start, const int* __restrict__ sorted,
    float* __restrict__ out){
  int wave = (blockIdx.x * 256 + threadIdx.x) >> 6;
  if (wave >= NN) return;
  int n = wave;
  int l = threadIdx.x & 63;
  int c = l * 2;
  int s0 = start[n], s1 = start[n + 1];
  uint qq = *(const uint*)(q_n + (size_t)n * 128 + c);
  float q0 = bf2f(qq & 0xffff), q1 = bf2f(qq >> 16);
  float acc0 = 0.f, acc1 = 0.f, denom = 0.f;
  for (int i = s0; i < s1; ++i){
    int e = sorted[i];
    int src = ei[e];
    uint2 kvp = *(const uint2*)(kv + (size_t)src * 256 + c * 2);   // k0,k1,v0,v1
    uint pp = *(const uint*)(ep + (size_t)e * 128 + c);
    float p0 = bf2f(pp & 0xffff), p1 = bf2f(pp >> 16);
    float k0 = bf2f(kvp.x & 0xffff) + p0, k1 = bf2f(kvp.x >> 16) + p1;
    float part = q0 * k0 + q1 * k1;
    for (int off = 16; off > 0; off >>= 1) part += __shfl_xor(part, off);  // per-32-lane head
    float ae = __expf(part * 0.125f);   // 1/sqrt(64); alpha ~ N(0,0.55^2), no max needed
    denom += ae;
    acc0 += ae * (bf2f(kvp.y & 0xffff) + p0);
    acc1 += ae * (bf2f(kvp.y >> 16) + p1);
  }
  float inv = 1.0f / (denom + 1e-16f);
  size_t o = (size_t)n * 128 + c;
  out[o]     += acc0 * inv;   // out already holds skip from k_node
  out[o + 1] += acc1 * inv;
}

extern "C" void kernel_launch(void* const* d_in, const int* in_sizes, int n_in,
                              void* d_out, int out_size, void* d_ws, size_t ws_size,
                              hipStream_t stream) {
  const float* x   = (const float*)d_in[0];
  const float* lu  = (const float*)d_in[1];
  const float* t   = (const float*)d_in[2];
  const float* msg = (const float*)d_in[3];
  const float* tw  = (const float*)d_in[4];
  const float* tb  = (const float*)d_in[5];
  const float* Wq  = (const float*)d_in[6];
  const float* bq  = (const float*)d_in[7];
  const float* Wk  = (const float*)d_in[8];
  const float* bk  = (const float*)d_in[9];
  const float* Wv  = (const float*)d_in[10];
  const float* bv  = (const float*)d_in[11];
  const float* We  = (const float*)d_in[12];
  const float* Wsk = (const float*)d_in[13];
  const float* bsk = (const float*)d_in[14];
  const int*   ei  = (const int*)d_in[15];
  float* out = (float*)d_out;

  char* w = (char*)d_ws;
  size_t off = 0;
  auto nxt = [&](size_t b){ size_t r = off; off += (b + 255) & ~(size_t)255; return r; };
  ushort* q_n  = (ushort*)(w + nxt((size_t)NN * 128 * 2));
  ushort* kv   = (ushort*)(w + nxt((size_t)NN * 256 * 2));
  ushort* epj  = (ushort*)(w + nxt((size_t)EE * 128 * 2));
  ushort* W4t  = (ushort*)(w + nxt((size_t)512 * 128 * 2));
  ushort* Wet  = (ushort*)(w + nxt((size_t)128 * 256 * 2));
  int* deg     = (int*)(w + nxt((size_t)NN * 4));
  int* start   = (int*)(w + nxt((size_t)(NN + 1) * 4));
  int* cursor  = (int*)(w + nxt((size_t)NN * 4));
  int* partial = (int*)(w + nxt((size_t)(NB_SCAN + 1) * 4));
  int* sorted  = (int*)(w + nxt((size_t)EE * 4));

  k_prep<<<(NN + 255) / 256, 256, 0, stream>>>(Wq, Wk, Wv, Wsk, We, W4t, Wet, deg);
  k_node<<<(NN + 63) / 64, 256, 0, stream>>>(x, W4t, bq, bk, bv, bsk, q_n, kv, out);
  k_edge<<<EE / 64, 256, 0, stream>>>(t, lu, msg, tw, tb, ei, Wet, epj);
  k_hist<<<(EE + 255) / 256, 256, 0, stream>>>(ei, deg);
  k_scan1<<<NB_SCAN, 256, 0, stream>>>(deg, start, partial);
  k_scan2<<<1, 64, 0, stream>>>(partial);
  k_scan3<<<(NN + 255) / 256, 256, 0, stream>>>(start, partial, cursor);
  k_place<<<(EE + 255) / 256, 256, 0, stream>>>(ei, cursor, sorted);
  k_gather<<<(NN * 64 + 255) / 256, 256, 0, stream>>>(q_n, kv, epj, ei, start, sorted, out);
}

// Round 3
// 508.932 us; speedup vs baseline: 2.0068x; 1.1849x over previous
//
#include <hip/hip_runtime.h>
#include <hip/hip_bf16.h>

#define NN 100000
#define EE 640000
#define NB_SCAN 98   // ceil(NN/1024)
#define NTILE 10000  // EE/64
#define G_EDGE 1024  // k_edge2 grid

typedef short bf16x8 __attribute__((ext_vector_type(8)));
typedef float f32x4 __attribute__((ext_vector_type(4)));

__device__ __forceinline__ ushort f2bf(float f){
  uint u = __float_as_uint(f);
  u += 0x7fffu + ((u >> 16) & 1u);   // round-to-nearest-even
  return (ushort)(u >> 16);
}
__device__ __forceinline__ float bf2f(ushort s){ return __uint_as_float(((uint)s) << 16); }
__device__ __forceinline__ uint pack2(float a, float b){ return ((uint)f2bf(b) << 16) | (uint)f2bf(a); }
__device__ __forceinline__ uint swz(uint row, uint colB, uint strideB){
  return row * strideB + (colB ^ ((row & 7u) << 4));
}

// ---------------- K0: weight prep (fp32 -> bf16, transposed [col][k]) + zero deg -----
__global__ void k_prep(const float* __restrict__ Wq, const float* __restrict__ Wk,
                       const float* __restrict__ Wv, const float* __restrict__ Wsk,
                       const float* __restrict__ We,
                       ushort* __restrict__ W4t, ushort* __restrict__ Wet,
                       int* __restrict__ deg){
  int tid = blockIdx.x * 256 + threadIdx.x;
  if (tid < 512 * 128){              // W4t[col 0..511][k 0..127], cols: q|k|v|skip
    int col = tid >> 7, k = tid & 127;
    const float* W = (col < 128) ? Wq : ((col < 256) ? Wk : ((col < 384) ? Wv : Wsk));
    W4t[tid] = f2bf(W[k * 128 + (col & 127)]);
  }
  if (tid < 128 * 256){              // Wet[col 0..127][k 0..255]
    int col = tid >> 8, k = tid & 255;
    Wet[tid] = f2bf(We[k * 128 + col]);
  }
  if (tid < NN) deg[tid] = 0;
}

// ---------------- K1: node GEMM x@[Wq|Wk|Wv|Wskip], 64-row tiles, bf16 MFMA ----------
__global__ __launch_bounds__(256) void k_node(
    const float* __restrict__ x, const ushort* __restrict__ W4t,
    const float* __restrict__ bq, const float* __restrict__ bk,
    const float* __restrict__ bv, const float* __restrict__ bsk,
    ushort* __restrict__ q_n, ushort* __restrict__ kv,
    float* __restrict__ out){
  __shared__ ushort As[64 * 128];
  __shared__ ushort Bs[128 * 128];
  char* Ab = (char*)As; char* Bb = (char*)Bs;
  int tid = threadIdx.x;
  int n0 = blockIdx.x * 64;
  {
    int row = tid >> 2, part = tid & 3;
    int gr = n0 + row;
    for (int j = 0; j < 4; j++){
      float4 a = make_float4(0.f,0.f,0.f,0.f), b = a;
      if (gr < NN){
        const float4* p = (const float4*)(x + (size_t)gr * 128 + part * 32 + j * 8);
        a = p[0]; b = p[1];
      }
      uint4 w; w.x = pack2(a.x,a.y); w.y = pack2(a.z,a.w); w.z = pack2(b.x,b.y); w.w = pack2(b.z,b.w);
      *(uint4*)(Ab + swz(row, (uint)(part * 64 + j * 16), 256)) = w;
    }
  }
  int wid = tid >> 6, l = tid & 63, lr = l & 15, lg = l >> 4;
  for (int chunk = 0; chunk < 4; ++chunk){
    if (chunk) __syncthreads();
    {
      int row = tid >> 1, half = tid & 1;
      const ushort* src = W4t + (size_t)(chunk * 128 + row) * 128 + half * 64;
      for (int j = 0; j < 8; j++){
        uint4 w = *(const uint4*)(src + j * 8);
        *(uint4*)(Bb + swz(row, (uint)(half * 128 + j * 16), 256)) = w;
      }
    }
    __syncthreads();
    f32x4 acc[8];
    for (int i = 0; i < 8; i++) acc[i] = (f32x4){0.f,0.f,0.f,0.f};
    for (int ks = 0; ks < 4; ++ks){
      bf16x8 a = *(bf16x8*)(Ab + swz(wid * 16 + lr, (uint)(ks * 64 + lg * 16), 256));
      for (int cf = 0; cf < 8; ++cf){
        bf16x8 b = *(bf16x8*)(Bb + swz(cf * 16 + lr, (uint)(ks * 64 + lg * 16), 256));
        acc[cf] = __builtin_amdgcn_mfma_f32_16x16x32_bf16(a, b, acc[cf], 0, 0, 0);
      }
    }
    for (int cf = 0; cf < 8; ++cf){
      for (int i = 0; i < 4; i++){
        int row = wid * 16 + lg * 4 + i;
        int gr = n0 + row;
        if (gr >= NN) continue;
        int col = cf * 16 + lr;
        float v = acc[cf][i];
        if (chunk == 0)      q_n[(size_t)gr * 128 + col] = f2bf(v + bq[col]);
        else if (chunk == 1) kv[(size_t)gr * 256 + ((col >> 1) << 2) + (col & 1)]     = f2bf(v + bk[col]);
        else if (chunk == 2) kv[(size_t)gr * 256 + ((col >> 1) << 2) + 2 + (col & 1)] = f2bf(v + bv[col]);
        else                 out[(size_t)gr * 128 + col] = v + bsk[col];
      }
    }
  }
}

// ---------------- K2 v2: persistent edge GEMM, B in registers, A triple-buffered -----
// 512 thr = 8 waves: waves 0-3 stage msg, waves 4-7 stage cos; all do MFMA.
// Per tile (64 edges x 128 cols, K=256): one raw s_barrier, loads fly across it.
__global__ __launch_bounds__(512, 2) void k_edge2(
    const float* __restrict__ tt, const float* __restrict__ lu,
    const float* __restrict__ msg, const float* __restrict__ tw,
    const float* __restrict__ tb, const int* __restrict__ ei,
    const ushort* __restrict__ Wet, ushort* __restrict__ ep){
  __shared__ ushort A[3][64][256];   // 96 KB, swizzled rows (512B stride)
  char* Ab = (char*)A;
  int tid = threadIdx.x;
  int wid = tid >> 6, l = tid & 63, lr = l & 15, lg = l >> 4;
  int rg = wid >> 1, cg = wid & 1;   // wave = (row-group 0..3) x (col-group 0..1)
  // B fragments: whole We tile (this wave's 64 cols x K=256) in 128 VGPRs, once.
  bf16x8 Bf[4][8];
  {
    const char* WB = (const char*)Wet;
    #pragma unroll
    for (int cf = 0; cf < 4; ++cf){
      #pragma unroll
      for (int ks = 0; ks < 8; ++ks)
        Bf[cf][ks] = *(const bf16x8*)(WB + (size_t)(cg*64 + cf*16 + lr)*512 + ks*64 + lg*16);
    }
  }
  int nT = (NTILE - (int)blockIdx.x + G_EDGE - 1) / G_EDGE;
  bool isMsg = (wid < 4);
  int er = (tid & 255) >> 2, qq = tid & 3;   // 64 edges x 4 quarters per role
  float4 mreg[8];
  float tvW = 0.f, luW = 0.f, tvN = 0.f;
  int eiN = 0;
  f32x4 acc[4];
  #pragma unroll
  for (int cf = 0; cf < 4; ++cf) acc[cf] = (f32x4){0.f,0.f,0.f,0.f};

  { // prologue: issue tile-0 staging loads
    int e = (int)blockIdx.x * 64 + er;
    if (isMsg){
      const float4* p = (const float4*)(msg + (size_t)e * 128 + qq * 32);
      #pragma unroll
      for (int j = 0; j < 8; ++j) mreg[j] = p[j];
    } else {
      tvN = tt[e]; eiN = ei[e];
      luW = lu[eiN];
      tvW = tvN;
    }
  }

  for (int i = 0; i <= nT; ++i){
    if (i < nT){
      // ---- write tile i into buf[i%3]
      char* dst = Ab + (i % 3) * 32768;
      if (isMsg){
        #pragma unroll
        for (int j = 0; j < 4; ++j){
          float4 a = mreg[2*j], b = mreg[2*j+1];
          uint4 w; w.x = pack2(a.x,a.y); w.y = pack2(a.z,a.w); w.z = pack2(b.x,b.y); w.w = pack2(b.z,b.w);
          *(uint4*)(dst + er*512 + ((uint)(256 + qq*64 + j*16) ^ ((uint)(er&7)<<4))) = w;
        }
      } else {
        float rel = tvW - luW;
        #pragma unroll
        for (int j = 0; j < 4; ++j){
          int k0 = qq*32 + j*8;
          float4 wa = *(const float4*)(tw + k0), wb = *(const float4*)(tw + k0 + 4);
          float4 ba = *(const float4*)(tb + k0), bb = *(const float4*)(tb + k0 + 4);
          float c0 = __cosf(fmaf(rel, wa.x, ba.x));
          float c1 = __cosf(fmaf(rel, wa.y, ba.y));
          float c2 = __cosf(fmaf(rel, wa.z, ba.z));
          float c3 = __cosf(fmaf(rel, wa.w, ba.w));
          float c4 = __cosf(fmaf(rel, wb.x, bb.x));
          float c5 = __cosf(fmaf(rel, wb.y, bb.y));
          float c6 = __cosf(fmaf(rel, wb.z, bb.z));
          float c7 = __cosf(fmaf(rel, wb.w, bb.w));
          uint4 w; w.x = pack2(c0,c1); w.y = pack2(c2,c3); w.z = pack2(c4,c5); w.w = pack2(c6,c7);
          *(uint4*)(dst + er*512 + ((uint)(qq*64 + j*16) ^ ((uint)(er&7)<<4))) = w;
        }
      }
      // ---- issue staging loads for tile i+1 (fly across barrier, land under MFMA)
      if (i + 1 < nT){
        int e = ((int)blockIdx.x + (i+1) * G_EDGE) * 64 + er;
        if (isMsg){
          const float4* p = (const float4*)(msg + (size_t)e * 128 + qq * 32);
          #pragma unroll
          for (int j = 0; j < 8; ++j) mreg[j] = p[j];
        } else {
          tvN = tt[e]; eiN = ei[e];
        }
      }
      __builtin_amdgcn_sched_barrier(0);
      asm volatile("s_waitcnt lgkmcnt(0)" ::: "memory");
      __builtin_amdgcn_s_barrier();
      __builtin_amdgcn_sched_barrier(0);
    }
    // ---- MFMA + store tile i-1 from buf[(i-1)%3]
    if (i > 0){
      char* src = Ab + ((i - 1) % 3) * 32768;
      #pragma unroll
      for (int ks = 0; ks < 8; ++ks){
        bf16x8 a = *(bf16x8*)(src + (rg*16+lr)*512 + (((uint)(ks*64 + lg*16)) ^ ((uint)(lr&7)<<4)));
        #pragma unroll
        for (int cf = 0; cf < 4; ++cf)
          acc[cf] = __builtin_amdgcn_mfma_f32_16x16x32_bf16(a, Bf[cf][ks], acc[cf], 0, 0, 0);
      }
      if (!isMsg && i + 1 < nT){ luW = lu[eiN]; tvW = tvN; }   // dependent lu, hidden by MFMA
      int e0s = ((int)blockIdx.x + (i-1) * G_EDGE) * 64;
      #pragma unroll
      for (int cf = 0; cf < 4; ++cf){
        #pragma unroll
        for (int i2 = 0; i2 < 4; ++i2){
          int row = rg*16 + lg*4 + i2, col = cg*64 + cf*16 + lr;
          ep[(size_t)(e0s + row)*128 + col] = f2bf(acc[cf][i2]);
        }
        acc[cf] = (f32x4){0.f,0.f,0.f,0.f};
      }
    } else {
      if (!isMsg && i + 1 < nT){ luW = lu[eiN]; tvW = tvN; }
    }
  }
}

// ---------------- Sort: histogram -> 2-level exclusive scan -> placement --------------
__global__ void k_hist(const int* __restrict__ ei, int* __restrict__ deg){
  int e = blockIdx.x * 256 + threadIdx.x;
  if (e < EE) atomicAdd(&deg[ei[EE + e]], 1);
}

__global__ __launch_bounds__(256) void k_scan1(const int* __restrict__ deg,
                                               int* __restrict__ start,
                                               int* __restrict__ partial){
  __shared__ int sums[256];
  int b = blockIdx.x, tid = threadIdx.x;
  int base = b * 1024 + tid * 4;
  int d0 = (base + 0 < NN) ? deg[base + 0] : 0;
  int d1 = (base + 1 < NN) ? deg[base + 1] : 0;
  int d2 = (base + 2 < NN) ? deg[base + 2] : 0;
  int d3 = (base + 3 < NN) ? deg[base + 3] : 0;
  int s = d0 + d1 + d2 + d3;
  sums[tid] = s;
  __syncthreads();
  for (int off = 1; off < 256; off <<= 1){
    int v = (tid >= off) ? sums[tid - off] : 0;
    __syncthreads();
    sums[tid] += v;
    __syncthreads();
  }
  int excl = sums[tid] - s;
  if (base + 0 < NN) start[base + 0] = excl;
  if (base + 1 < NN) start[base + 1] = excl + d0;
  if (base + 2 < NN) start[base + 2] = excl + d0 + d1;
  if (base + 3 < NN) start[base + 3] = excl + d0 + d1 + d2;
  if (tid == 255) partial[b] = sums[255];
}

__global__ void k_scan2(int* __restrict__ partial){
  if (threadIdx.x == 0){
    int run = 0;
    for (int b = 0; b < NB_SCAN; b++){ int t = partial[b]; partial[b] = run; run += t; }
  }
}

__global__ void k_scan3(int* __restrict__ start, const int* __restrict__ partial,
                        int* __restrict__ cursor){
  int i = blockIdx.x * 256 + threadIdx.x;
  if (i < NN){
    int v = start[i] + partial[i >> 10];
    start[i] = v;
    cursor[i] = v;
  }
  if (i == 0) start[NN] = EE;
}

__global__ void k_place(const int* __restrict__ ei, int* __restrict__ cursor,
                        uint2* __restrict__ sorted2){
  int e = blockIdx.x * 256 + threadIdx.x;
  if (e < EE){
    int dst = ei[EE + e];
    int src = ei[e];
    int pos = atomicAdd(&cursor[dst], 1);
    sorted2[pos] = make_uint2((uint)e, (uint)src);  // pre-gathered src kills a dep load
  }
}

// ---------------- K3: per-node gather: logits, softmax, weighted sum ------------------
// one 64-lane wave per dst node; lane l owns channels 2l,2l+1 (head = l>>5); unroll x2
__global__ __launch_bounds__(256) void k_gather(
    const ushort* __restrict__ q_n, const ushort* __restrict__ kv,
    const ushort* __restrict__ ep, const int* __restrict__ start,
    const uint2* __restrict__ sorted2, float* __restrict__ out){
  int wave = (blockIdx.x * 256 + threadIdx.x) >> 6;
  if (wave >= NN) return;
  int n = wave;
  int l = threadIdx.x & 63;
  int c = l * 2;
  int s0 = start[n], s1 = start[n + 1];
  uint qq = *(const uint*)(q_n + (size_t)n * 128 + c);
  float q0 = bf2f(qq & 0xffff), q1 = bf2f(qq >> 16);
  float acc0 = 0.f, acc1 = 0.f, denom = 0.f;
  int i = s0;
  for (; i + 2 <= s1; i += 2){
    uint2 p0 = sorted2[i], p1 = sorted2[i + 1];
    uint2 kv0 = *(const uint2*)(kv + (size_t)p0.y * 256 + c * 2);
    uint2 kv1 = *(const uint2*)(kv + (size_t)p1.y * 256 + c * 2);
    uint e0 = *(const uint*)(ep + (size_t)p0.x * 128 + c);
    uint e1 = *(const uint*)(ep + (size_t)p1.x * 128 + c);
    float pa0 = bf2f(e0 & 0xffff), pa1 = bf2f(e0 >> 16);
    float pb0 = bf2f(e1 & 0xffff), pb1 = bf2f(e1 >> 16);
    float ka = q0 * (bf2f(kv0.x & 0xffff) + pa0) + q1 * (bf2f(kv0.x >> 16) + pa1);
    float kb = q0 * (bf2f(kv1.x & 0xffff) + pb0) + q1 * (bf2f(kv1.x >> 16) + pb1);
    #pragma unroll
    for (int off = 16; off > 0; off >>= 1){
      ka += __shfl_xor(ka, off);
      kb += __shfl_xor(kb, off);
    }
    float ea = __expf(ka * 0.125f), eb = __expf(kb * 0.125f);
    denom += ea + eb;
    acc0 += ea * (bf2f(kv0.y & 0xffff) + pa0) + eb * (bf2f(kv1.y & 0xffff) + pb0);
    acc1 += ea * (bf2f(kv0.y >> 16) + pa1) + eb * (bf2f(kv1.y >> 16) + pb1);
  }
  if (i < s1){
    uint2 p0 = sorted2[i];
    uint2 kv0 = *(const uint2*)(kv + (size_t)p0.y * 256 + c * 2);
    uint e0 = *(const uint*)(ep + (size_t)p0.x * 128 + c);
    float pa0 = bf2f(e0 & 0xffff), pa1 = bf2f(e0 >> 16);
    float ka = q0 * (bf2f(kv0.x & 0xffff) + pa0) + q1 * (bf2f(kv0.x >> 16) + pa1);
    #pragma unroll
    for (int off = 16; off > 0; off >>= 1) ka += __shfl_xor(ka, off);
    float ea = __expf(ka * 0.125f);
    denom += ea;
    acc0 += ea * (bf2f(kv0.y & 0xffff) + pa0);
    acc1 += ea * (bf2f(kv0.y >> 16) + pa1);
  }
  float inv = 1.0f / (denom + 1e-16f);
  size_t o = (size_t)n * 128 + c;
  out[o]     += acc0 * inv;
  out[o + 1] += acc1 * inv;
}

extern "C" void kernel_launch(void* const* d_in, const int* in_sizes, int n_in,
                              void* d_out, int out_size, void* d_ws, size_t ws_size,
                              hipStream_t stream) {
  const float* x   = (const float*)d_in[0];
  const float* lu  = (const float*)d_in[1];
  const float* t   = (const float*)d_in[2];
  const float* msg = (const float*)d_in[3];
  const float* tw  = (const float*)d_in[4];
  const float* tb  = (const float*)d_in[5];
  const float* Wq  = (const float*)d_in[6];
  const float* bq  = (const float*)d_in[7];
  const float* Wk  = (const float*)d_in[8];
  const float* bk  = (const float*)d_in[9];
  const float* Wv  = (const float*)d_in[10];
  const float* bv  = (const float*)d_in[11];
  const float* We  = (const float*)d_in[12];
  const float* Wsk = (const float*)d_in[13];
  const float* bsk = (const float*)d_in[14];
  const int*   ei  = (const int*)d_in[15];
  float* out = (float*)d_out;

  char* w = (char*)d_ws;
  size_t off = 0;
  auto nxt = [&](size_t b){ size_t r = off; off += (b + 255) & ~(size_t)255; return r; };
  ushort* q_n   = (ushort*)(w + nxt((size_t)NN * 128 * 2));
  ushort* kv    = (ushort*)(w + nxt((size_t)NN * 256 * 2));
  ushort* epj   = (ushort*)(w + nxt((size_t)EE * 128 * 2));
  ushort* W4t   = (ushort*)(w + nxt((size_t)512 * 128 * 2));
  ushort* Wet   = (ushort*)(w + nxt((size_t)128 * 256 * 2));
  int* deg      = (int*)(w + nxt((size_t)NN * 4));
  int* start    = (int*)(w + nxt((size_t)(NN + 1) * 4));
  int* cursor   = (int*)(w + nxt((size_t)NN * 4));
  int* partial  = (int*)(w + nxt((size_t)(NB_SCAN + 1) * 4));
  uint2* sorted2 = (uint2*)(w + nxt((size_t)EE * 8));

  k_prep<<<(NN + 255) / 256, 256, 0, stream>>>(Wq, Wk, Wv, Wsk, We, W4t, Wet, deg);
  k_node<<<(NN + 63) / 64, 256, 0, stream>>>(x, W4t, bq, bk, bv, bsk, q_n, kv, out);
  k_edge2<<<G_EDGE, 512, 0, stream>>>(t, lu, msg, tw, tb, ei, Wet, epj);
  k_hist<<<(EE + 255) / 256, 256, 0, stream>>>(ei, deg);
  k_scan1<<<NB_SCAN, 256, 0, stream>>>(deg, start, partial);
  k_scan2<<<1, 64, 0, stream>>>(partial);
  k_scan3<<<(NN + 255) / 256, 256, 0, stream>>>(start, partial, cursor);
  k_place<<<(EE + 255) / 256, 256, 0, stream>>>(ei, cursor, sorted2);
  k_gather<<<(NN * 64 + 255) / 256, 256, 0, stream>>>(q_n, kv, epj, start, sorted2, out);
}

// Round 4
// 479.673 us; speedup vs baseline: 2.1292x; 1.0610x over previous
//
#include <hip/hip_runtime.h>
#include <hip/hip_bf16.h>

#define NN 100000
#define EE 640000
#define NB_SCAN 98   // ceil(NN/1024)
#define G_E3 2048    // k_edge3 blocks (8192 waves; 80000 wave-tasks)

typedef short bf16x8 __attribute__((ext_vector_type(8)));
typedef float f32x4 __attribute__((ext_vector_type(4)));

__device__ __forceinline__ ushort f2bf(float f){
  uint u = __float_as_uint(f);
  u += 0x7fffu + ((u >> 16) & 1u);   // round-to-nearest-even
  return (ushort)(u >> 16);
}
__device__ __forceinline__ float bf2f(ushort s){ return __uint_as_float(((uint)s) << 16); }
__device__ __forceinline__ uint pack2(float a, float b){ return ((uint)f2bf(b) << 16) | (uint)f2bf(a); }
__device__ __forceinline__ uint swz(uint row, uint colB, uint strideB){
  return row * strideB + (colB ^ ((row & 7u) << 4));
}

// ---------------- K0: weight prep (fp32 -> bf16, transposed [col][k]) + zero deg -----
__global__ void k_prep(const float* __restrict__ Wq, const float* __restrict__ Wk,
                       const float* __restrict__ Wv, const float* __restrict__ Wsk,
                       const float* __restrict__ We,
                       ushort* __restrict__ W4t, ushort* __restrict__ Wet,
                       int* __restrict__ deg){
  int tid = blockIdx.x * 256 + threadIdx.x;
  if (tid < 512 * 128){              // W4t[col 0..511][k 0..127], cols: q|k|v|skip
    int col = tid >> 7, k = tid & 127;
    const float* W = (col < 128) ? Wq : ((col < 256) ? Wk : ((col < 384) ? Wv : Wsk));
    W4t[tid] = f2bf(W[k * 128 + (col & 127)]);
  }
  if (tid < 128 * 256){              // Wet[col 0..127][k 0..255]
    int col = tid >> 8, k = tid & 255;
    Wet[tid] = f2bf(We[k * 128 + col]);
  }
  if (tid < NN) deg[tid] = 0;
}

// ---------------- K1: node GEMM x@[Wq|Wk|Wv|Wskip], 64-row tiles, bf16 MFMA ----------
__global__ __launch_bounds__(256) void k_node(
    const float* __restrict__ x, const ushort* __restrict__ W4t,
    const float* __restrict__ bq, const float* __restrict__ bk,
    const float* __restrict__ bv, const float* __restrict__ bsk,
    ushort* __restrict__ q_n, ushort* __restrict__ kv,
    float* __restrict__ out){
  __shared__ ushort As[64 * 128];
  __shared__ ushort Bs[128 * 128];
  char* Ab = (char*)As; char* Bb = (char*)Bs;
  int tid = threadIdx.x;
  int n0 = blockIdx.x * 64;
  {
    int row = tid >> 2, part = tid & 3;
    int gr = n0 + row;
    for (int j = 0; j < 4; j++){
      float4 a = make_float4(0.f,0.f,0.f,0.f), b = a;
      if (gr < NN){
        const float4* p = (const float4*)(x + (size_t)gr * 128 + part * 32 + j * 8);
        a = p[0]; b = p[1];
      }
      uint4 w; w.x = pack2(a.x,a.y); w.y = pack2(a.z,a.w); w.z = pack2(b.x,b.y); w.w = pack2(b.z,b.w);
      *(uint4*)(Ab + swz(row, (uint)(part * 64 + j * 16), 256)) = w;
    }
  }
  int wid = tid >> 6, l = tid & 63, lr = l & 15, lg = l >> 4;
  for (int chunk = 0; chunk < 4; ++chunk){
    if (chunk) __syncthreads();
    {
      int row = tid >> 1, half = tid & 1;
      const ushort* src = W4t + (size_t)(chunk * 128 + row) * 128 + half * 64;
      for (int j = 0; j < 8; j++){
        uint4 w = *(const uint4*)(src + j * 8);
        *(uint4*)(Bb + swz(row, (uint)(half * 128 + j * 16), 256)) = w;
      }
    }
    __syncthreads();
    f32x4 acc[8];
    for (int i = 0; i < 8; i++) acc[i] = (f32x4){0.f,0.f,0.f,0.f};
    for (int ks = 0; ks < 4; ++ks){
      bf16x8 a = *(bf16x8*)(Ab + swz(wid * 16 + lr, (uint)(ks * 64 + lg * 16), 256));
      for (int cf = 0; cf < 8; ++cf){
        bf16x8 b = *(bf16x8*)(Bb + swz(cf * 16 + lr, (uint)(ks * 64 + lg * 16), 256));
        acc[cf] = __builtin_amdgcn_mfma_f32_16x16x32_bf16(a, b, acc[cf], 0, 0, 0);
      }
    }
    for (int cf = 0; cf < 8; ++cf){
      for (int i = 0; i < 4; i++){
        int row = wid * 16 + lg * 4 + i;
        int gr = n0 + row;
        if (gr >= NN) continue;
        int col = cf * 16 + lr;
        float v = acc[cf][i];
        if (chunk == 0)      q_n[(size_t)gr * 128 + col] = f2bf(v + bq[col]);
        else if (chunk == 1) kv[(size_t)gr * 256 + ((col >> 1) << 2) + (col & 1)]     = f2bf(v + bk[col]);
        else if (chunk == 2) kv[(size_t)gr * 256 + ((col >> 1) << 2) + 2 + (col & 1)] = f2bf(v + bv[col]);
        else                 out[(size_t)gr * 128 + col] = v + bsk[col];
      }
    }
  }
}

// ---------------- k_rel: rel[e] = t[e] - lu[src[e]] (kills dependent chain in GEMM) --
__global__ void k_rel(const float* __restrict__ tt, const float* __restrict__ lu,
                      const int* __restrict__ ei, float* __restrict__ rel){
  int e = blockIdx.x * 256 + threadIdx.x;
  if (e < EE) rel[e] = tt[e] - lu[ei[e]];
}

// ---------------- K2 v3: edge GEMM, NO LDS, NO barriers. -----------------------------
// Operands swapped: A = We^T (rows=out channels, in 128 VGPRs), B = edge features
// built directly in registers (lane lr = edge, lg = k-octet): k<128 cos, k>=128 msg.
// Wave handles 16 edges x 64 channels (half = gw&1); wave pairs share msg rows (L1).
__global__ __launch_bounds__(256, 2) void k_edge3(
    const float* __restrict__ rel, const float* __restrict__ msg,
    const float* __restrict__ tw, const float* __restrict__ tb,
    const ushort* __restrict__ Wet, ushort* __restrict__ ep){
  int tid = threadIdx.x;
  int wid = tid >> 6, l = tid & 63, lr = l & 15, lg = l >> 4;
  int gw = (int)blockIdx.x * 4 + wid;   // global wave id (8192 total)
  int half = gw & 1;                    // channel half: 0 -> ch 0..63, 1 -> ch 64..127
  // A-fragments: Wet rows (half*64 .. +64) x K=256, loaded once (128 VGPRs)
  bf16x8 Af[4][8];
  const char* WB = (const char*)Wet;
  #pragma unroll
  for (int rt = 0; rt < 4; ++rt)
    #pragma unroll
    for (int ks = 0; ks < 8; ++ks)
      Af[rt][ks] = *(const bf16x8*)(WB + (size_t)(half*64 + rt*16 + lr)*512 + ks*64 + lg*16);

  for (int g = gw >> 1; g < EE/16; g += G_E3 * 2){
    int e0 = g * 16;
    // issue msg loads first (8 independent float4, fly under cos compute)
    float4 m[8];
    const float* MB = msg + (size_t)(e0 + lr) * 128 + lg * 8;
    #pragma unroll
    for (int ks = 0; ks < 4; ++ks){
      m[2*ks]   = *(const float4*)(MB + ks * 32);
      m[2*ks+1] = *(const float4*)(MB + ks * 32 + 4);
    }
    float relv = rel[e0 + lr];
    bf16x8 B[8];
    #pragma unroll
    for (int ks = 0; ks < 4; ++ks){     // k = ks*32 + lg*8 .. +8 : cos features
      int k0 = ks * 32 + lg * 8;
      float4 wa = *(const float4*)(tw + k0), wb = *(const float4*)(tw + k0 + 4);
      float4 ba = *(const float4*)(tb + k0), bb = *(const float4*)(tb + k0 + 4);
      float c0 = __cosf(fmaf(relv, wa.x, ba.x));
      float c1 = __cosf(fmaf(relv, wa.y, ba.y));
      float c2 = __cosf(fmaf(relv, wa.z, ba.z));
      float c3 = __cosf(fmaf(relv, wa.w, ba.w));
      float c4 = __cosf(fmaf(relv, wb.x, bb.x));
      float c5 = __cosf(fmaf(relv, wb.y, bb.y));
      float c6 = __cosf(fmaf(relv, wb.z, bb.z));
      float c7 = __cosf(fmaf(relv, wb.w, bb.w));
      uint4 w; w.x = pack2(c0,c1); w.y = pack2(c2,c3); w.z = pack2(c4,c5); w.w = pack2(c6,c7);
      B[ks] = *(bf16x8*)&w;
    }
    #pragma unroll
    for (int ks = 0; ks < 4; ++ks){     // k = 128 + ks*32 + lg*8 : msg features
      float4 a = m[2*ks], b = m[2*ks+1];
      uint4 w; w.x = pack2(a.x,a.y); w.y = pack2(a.z,a.w); w.z = pack2(b.x,b.y); w.w = pack2(b.z,b.w);
      B[4+ks] = *(bf16x8*)&w;
    }
    f32x4 acc[4];
    #pragma unroll
    for (int rt = 0; rt < 4; ++rt) acc[rt] = (f32x4){0.f,0.f,0.f,0.f};
    #pragma unroll
    for (int ks = 0; ks < 8; ++ks)
      #pragma unroll
      for (int rt = 0; rt < 4; ++rt)
        acc[rt] = __builtin_amdgcn_mfma_f32_16x16x32_bf16(Af[rt][ks], B[ks], acc[rt], 0, 0, 0);
    // D: col = lane&15 = edge, row = (lane>>4)*4+i = channel -> 4 contiguous ushorts
    #pragma unroll
    for (int rt = 0; rt < 4; ++rt){
      uint2 w = make_uint2(pack2(acc[rt][0], acc[rt][1]), pack2(acc[rt][2], acc[rt][3]));
      *(uint2*)(ep + (size_t)(e0 + lr) * 128 + half * 64 + rt * 16 + lg * 4) = w;
    }
  }
}

// ---------------- Sort: histogram -> 2-level exclusive scan -> placement --------------
__global__ void k_hist(const int* __restrict__ ei, int* __restrict__ deg){
  int e = blockIdx.x * 256 + threadIdx.x;
  if (e < EE) atomicAdd(&deg[ei[EE + e]], 1);
}

__global__ __launch_bounds__(256) void k_scan1(const int* __restrict__ deg,
                                               int* __restrict__ start,
                                               int* __restrict__ partial){
  __shared__ int sums[256];
  int b = blockIdx.x, tid = threadIdx.x;
  int base = b * 1024 + tid * 4;
  int d0 = (base + 0 < NN) ? deg[base + 0] : 0;
  int d1 = (base + 1 < NN) ? deg[base + 1] : 0;
  int d2 = (base + 2 < NN) ? deg[base + 2] : 0;
  int d3 = (base + 3 < NN) ? deg[base + 3] : 0;
  int s = d0 + d1 + d2 + d3;
  sums[tid] = s;
  __syncthreads();
  for (int off = 1; off < 256; off <<= 1){
    int v = (tid >= off) ? sums[tid - off] : 0;
    __syncthreads();
    sums[tid] += v;
    __syncthreads();
  }
  int excl = sums[tid] - s;
  if (base + 0 < NN) start[base + 0] = excl;
  if (base + 1 < NN) start[base + 1] = excl + d0;
  if (base + 2 < NN) start[base + 2] = excl + d0 + d1;
  if (base + 3 < NN) start[base + 3] = excl + d0 + d1 + d2;
  if (tid == 255) partial[b] = sums[255];
}

__global__ void k_scan2(int* __restrict__ partial){
  if (threadIdx.x == 0){
    int run = 0;
    for (int b = 0; b < NB_SCAN; b++){ int t = partial[b]; partial[b] = run; run += t; }
  }
}

__global__ void k_scan3(int* __restrict__ start, const int* __restrict__ partial,
                        int* __restrict__ cursor){
  int i = blockIdx.x * 256 + threadIdx.x;
  if (i < NN){
    int v = start[i] + partial[i >> 10];
    start[i] = v;
    cursor[i] = v;
  }
  if (i == 0) start[NN] = EE;
}

__global__ void k_place(const int* __restrict__ ei, int* __restrict__ cursor,
                        uint2* __restrict__ sorted2){
  int e = blockIdx.x * 256 + threadIdx.x;
  if (e < EE){
    int dst = ei[EE + e];
    int src = ei[e];
    int pos = atomicAdd(&cursor[dst], 1);
    sorted2[pos] = make_uint2((uint)e, (uint)src);  // pre-gathered src kills a dep load
  }
}

// ---------------- K3: per-node gather: logits, softmax, weighted sum ------------------
__global__ __launch_bounds__(256) void k_gather(
    const ushort* __restrict__ q_n, const ushort* __restrict__ kv,
    const ushort* __restrict__ ep, const int* __restrict__ start,
    const uint2* __restrict__ sorted2, float* __restrict__ out){
  int wave = (blockIdx.x * 256 + threadIdx.x) >> 6;
  if (wave >= NN) return;
  int n = wave;
  int l = threadIdx.x & 63;
  int c = l * 2;
  int s0 = start[n], s1 = start[n + 1];
  uint qq = *(const uint*)(q_n + (size_t)n * 128 + c);
  float q0 = bf2f(qq & 0xffff), q1 = bf2f(qq >> 16);
  float acc0 = 0.f, acc1 = 0.f, denom = 0.f;
  int i = s0;
  for (; i + 2 <= s1; i += 2){
    uint2 p0 = sorted2[i], p1 = sorted2[i + 1];
    uint2 kv0 = *(const uint2*)(kv + (size_t)p0.y * 256 + c * 2);
    uint2 kv1 = *(const uint2*)(kv + (size_t)p1.y * 256 + c * 2);
    uint e0 = *(const uint*)(ep + (size_t)p0.x * 128 + c);
    uint e1 = *(const uint*)(ep + (size_t)p1.x * 128 + c);
    float pa0 = bf2f(e0 & 0xffff), pa1 = bf2f(e0 >> 16);
    float pb0 = bf2f(e1 & 0xffff), pb1 = bf2f(e1 >> 16);
    float ka = q0 * (bf2f(kv0.x & 0xffff) + pa0) + q1 * (bf2f(kv0.x >> 16) + pa1);
    float kb = q0 * (bf2f(kv1.x & 0xffff) + pb0) + q1 * (bf2f(kv1.x >> 16) + pb1);
    #pragma unroll
    for (int off = 16; off > 0; off >>= 1){
      ka += __shfl_xor(ka, off);
      kb += __shfl_xor(kb, off);
    }
    float ea = __expf(ka * 0.125f), eb = __expf(kb * 0.125f);
    denom += ea + eb;
    acc0 += ea * (bf2f(kv0.y & 0xffff) + pa0) + eb * (bf2f(kv1.y & 0xffff) + pb0);
    acc1 += ea * (bf2f(kv0.y >> 16) + pa1) + eb * (bf2f(kv1.y >> 16) + pb1);
  }
  if (i < s1){
    uint2 p0 = sorted2[i];
    uint2 kv0 = *(const uint2*)(kv + (size_t)p0.y * 256 + c * 2);
    uint e0 = *(const uint*)(ep + (size_t)p0.x * 128 + c);
    float pa0 = bf2f(e0 & 0xffff), pa1 = bf2f(e0 >> 16);
    float ka = q0 * (bf2f(kv0.x & 0xffff) + pa0) + q1 * (bf2f(kv0.x >> 16) + pa1);
    #pragma unroll
    for (int off = 16; off > 0; off >>= 1) ka += __shfl_xor(ka, off);
    float ea = __expf(ka * 0.125f);
    denom += ea;
    acc0 += ea * (bf2f(kv0.y & 0xffff) + pa0);
    acc1 += ea * (bf2f(kv0.y >> 16) + pa1);
  }
  float inv = 1.0f / (denom + 1e-16f);
  size_t o = (size_t)n * 128 + c;
  out[o]     += acc0 * inv;
  out[o + 1] += acc1 * inv;
}

extern "C" void kernel_launch(void* const* d_in, const int* in_sizes, int n_in,
                              void* d_out, int out_size, void* d_ws, size_t ws_size,
                              hipStream_t stream) {
  const float* x   = (const float*)d_in[0];
  const float* lu  = (const float*)d_in[1];
  const float* t   = (const float*)d_in[2];
  const float* msg = (const float*)d_in[3];
  const float* tw  = (const float*)d_in[4];
  const float* tb  = (const float*)d_in[5];
  const float* Wq  = (const float*)d_in[6];
  const float* bq  = (const float*)d_in[7];
  const float* Wk  = (const float*)d_in[8];
  const float* bk  = (const float*)d_in[9];
  const float* Wv  = (const float*)d_in[10];
  const float* bv  = (const float*)d_in[11];
  const float* We  = (const float*)d_in[12];
  const float* Wsk = (const float*)d_in[13];
  const float* bsk = (const float*)d_in[14];
  const int*   ei  = (const int*)d_in[15];
  float* out = (float*)d_out;

  char* w = (char*)d_ws;
  size_t off = 0;
  auto nxt = [&](size_t b){ size_t r = off; off += (b + 255) & ~(size_t)255; return r; };
  ushort* q_n   = (ushort*)(w + nxt((size_t)NN * 128 * 2));
  ushort* kv    = (ushort*)(w + nxt((size_t)NN * 256 * 2));
  ushort* epj   = (ushort*)(w + nxt((size_t)EE * 128 * 2));
  ushort* W4t   = (ushort*)(w + nxt((size_t)512 * 128 * 2));
  ushort* Wet   = (ushort*)(w + nxt((size_t)128 * 256 * 2));
  int* deg      = (int*)(w + nxt((size_t)NN * 4));
  int* start    = (int*)(w + nxt((size_t)(NN + 1) * 4));
  int* cursor   = (int*)(w + nxt((size_t)NN * 4));
  int* partial  = (int*)(w + nxt((size_t)(NB_SCAN + 1) * 4));
  uint2* sorted2 = (uint2*)(w + nxt((size_t)EE * 8));
  float* rel    = (float*)(w + nxt((size_t)EE * 4));

  k_prep<<<(NN + 255) / 256, 256, 0, stream>>>(Wq, Wk, Wv, Wsk, We, W4t, Wet, deg);
  k_node<<<(NN + 63) / 64, 256, 0, stream>>>(x, W4t, bq, bk, bv, bsk, q_n, kv, out);
  k_rel<<<(EE + 255) / 256, 256, 0, stream>>>(t, lu, ei, rel);
  k_edge3<<<G_E3, 256, 0, stream>>>(rel, msg, tw, tb, Wet, epj);
  k_hist<<<(EE + 255) / 256, 256, 0, stream>>>(ei, deg);
  k_scan1<<<NB_SCAN, 256, 0, stream>>>(deg, start, partial);
  k_scan2<<<1, 64, 0, stream>>>(partial);
  k_scan3<<<(NN + 255) / 256, 256, 0, stream>>>(start, partial, cursor);
  k_place<<<(EE + 255) / 256, 256, 0, stream>>>(ei, cursor, sorted2);
  k_gather<<<(NN * 64 + 255) / 256, 256, 0, stream>>>(q_n, kv, epj, start, sorted2, out);
}